// Round 1
// baseline (117.625 us; speedup 1.0000x reference)
//
#include <hip/hip_runtime.h>
#include <hip/hip_bf16.h>
#include <math.h>

// Problem constants (from reference): M=N=192, C=256, K=5, R=4096,
// POOL=2, TILES=3  -> S = 6 samples per axis, pooled = 3x3x256, FC 2304->4.
constexpr int MH = 192;
constexpr int NH = 192;
constexpr int CH = 256;
constexpr int KH = 5;
constexpr int SS = 6;   // POOL*TILES
constexpr int TT = 3;   // TILES

__global__ __launch_bounds__(256)
void rcnn_head_kernel(const float* __restrict__ features,   // (1,192,192,256)
                      const float* __restrict__ obj_out,    // (192,192,10)
                      const float* __restrict__ reg_out,    // (192,192,20)
                      const float* __restrict__ anchors,    // (R,4) cx,cy,w,h
                      const float* __restrict__ boxes,      // (R,4) x0,y0,w,h
                      const float* __restrict__ W_fc,       // (2304,4)
                      const float* __restrict__ b_fc,       // (4,)
                      const int*   __restrict__ anchor_px,  // (5,)
                      const int*   __restrict__ field_p,    // scalar
                      float*       __restrict__ out)        // (R,14)
{
    const int r = blockIdx.x;
    const int c = threadIdx.x;           // channel 0..255
    const float field = (float)field_p[0];

    // ---- per-ROI scalars (uniform across the block; broadcast loads) ----
    const float ax = anchors[r * 4 + 0];
    const float ay = anchors[r * 4 + 1];
    const float aw = anchors[r * 4 + 2];
    const float ah = anchors[r * 4 + 3];

    // kk = index of anchor size matching (int)ah
    const int awi = (int)ah;
    int kk = 0;
#pragma unroll
    for (int i = 0; i < KH; ++i) {
        if (anchor_px[i] == awi) kk = i;
    }
    const int px = (int)((ax - field * 0.5f) / field);
    const int py = (int)((ay - field * 0.5f) / field);
    const int base = (py * NH + px) * KH + kk;

    // obj softmax (2 logits)
    const float o0 = obj_out[base * 2 + 0];
    const float o1 = obj_out[base * 2 + 1];
    const float om = fmaxf(o0, o1);
    const float e0 = expf(o0 - om);
    const float e1 = expf(o1 - om);
    const float einv = 1.0f / (e0 + e1);
    const float obj0 = e0 * einv;
    const float obj1 = e1 * einv;

    // reg -> rpn box (unparameterize vs anchor)
    const float rg0 = reg_out[base * 4 + 0];
    const float rg1 = reg_out[base * 4 + 1];
    const float rg2 = reg_out[base * 4 + 2];
    const float rg3 = reg_out[base * 4 + 3];
    const float cx = rg0 * aw + ax;
    const float cy = rg1 * ah + ay;
    const float bw = aw * expf(rg2);
    const float bh = ah * expf(rg3);

    // ---- roialign sample coordinates (6 per axis) ----
    const float x0f = cx - bw * 0.5f;
    const float y0f = cy - bh * 0.5f;
    int   xi[SS], yi[SS];
    float wx[SS], wy[SS];
#pragma unroll
    for (int i = 0; i < SS; ++i) {
        const float off = (i + 0.5f) * (1.0f / SS);
        float fx = (x0f + off * bw) / field - 0.5f;
        float fl = floorf(fx);
        fl = fminf(fmaxf(fl, 0.0f), (float)(NH - 2));
        xi[i] = (int)fl;
        wx[i] = fminf(fmaxf(fx - fl, 0.0f), 1.0f);

        float fy = (y0f + off * bh) / field - 0.5f;
        float fy0 = floorf(fy);
        fy0 = fminf(fmaxf(fy0, 0.0f), (float)(MH - 2));
        yi[i] = (int)fy0;
        wy[i] = fminf(fmaxf(fy - fy0, 0.0f), 1.0f);
    }

    // ---- gather + bilinear + fused 2x2 maxpool -> pooled[3][3] ----
    float pooled[TT][TT];
#pragma unroll
    for (int ty = 0; ty < TT; ++ty) {
#pragma unroll
        for (int tx = 0; tx < TT; ++tx) {
            float mx = -INFINITY;
#pragma unroll
            for (int sy = 0; sy < 2; ++sy) {
#pragma unroll
                for (int sx = 0; sx < 2; ++sx) {
                    const int iy = ty * 2 + sy;
                    const int ix = tx * 2 + sx;
                    const int y0 = yi[iy];
                    const int x0 = xi[ix];
                    const float* p = features + ((size_t)(y0 * NH + x0)) * CH + c;
                    const float v00 = p[0];
                    const float v01 = p[CH];
                    const float v10 = p[NH * CH];
                    const float v11 = p[NH * CH + CH];
                    const float wxx = wx[ix];
                    const float wyy = wy[iy];
                    // match reference arithmetic exactly: (1-w)*a + w*b
                    const float top = (1.0f - wxx) * v00 + wxx * v01;
                    const float bot = (1.0f - wxx) * v10 + wxx * v11;
                    const float v = (1.0f - wyy) * top + wyy * bot;
                    mx = fmaxf(mx, v);
                }
            }
            pooled[ty][tx] = mx;
        }
    }

    // ---- FC: per-channel partials, W_fc row (t*256 + c) as float4 ----
    float s0 = 0.f, s1 = 0.f, s2 = 0.f, s3 = 0.f;
#pragma unroll
    for (int t = 0; t < TT * TT; ++t) {
        const float p = pooled[t / TT][t % TT];
        const float4 w4 = *reinterpret_cast<const float4*>(&W_fc[(size_t)(t * CH + c) * 4]);
        s0 += p * w4.x;
        s1 += p * w4.y;
        s2 += p * w4.z;
        s3 += p * w4.w;
    }

    // wave (64-lane) shuffle reduction
#pragma unroll
    for (int off = 32; off > 0; off >>= 1) {
        s0 += __shfl_down(s0, off);
        s1 += __shfl_down(s1, off);
        s2 += __shfl_down(s2, off);
        s3 += __shfl_down(s3, off);
    }

    __shared__ float red[4][4];
    const int wave = c >> 6;
    const int lane = c & 63;
    if (lane == 0) {
        red[wave][0] = s0;
        red[wave][1] = s1;
        red[wave][2] = s2;
        red[wave][3] = s3;
    }
    __syncthreads();

    if (c == 0) {
        const float a0 = b_fc[0] + red[0][0] + red[1][0] + red[2][0] + red[3][0];
        const float a1 = b_fc[1] + red[0][1] + red[1][1] + red[2][1] + red[3][1];
        const float a2 = b_fc[2] + red[0][2] + red[1][2] + red[2][2] + red[3][2];
        const float a3 = b_fc[3] + red[0][3] + red[1][3] + red[2][3] + red[3][3];

        // align_boxes = unparameterize(align_reg, rpn_boxes)
        const float acx = a0 * bw + cx;
        const float acy = a1 * bh + cy;
        const float aww = bw * expf(a2);
        const float ahh = bh * expf(a3);

        // align_reg_label = parameterize(rpn_boxes, boxes)
        const float gx = boxes[r * 4 + 0];
        const float gy = boxes[r * 4 + 1];
        const float gw = boxes[r * 4 + 2];
        const float gh = boxes[r * 4 + 3];
        const float txl = (gx + gw * 0.5f - cx) / bw;
        const float tyl = (gy + gh * 0.5f - cy) / bh;
        const float twl = logf(gw / bw);
        const float thl = logf(gh / bh);

        float* o = out + (size_t)r * 14;
        o[0]  = obj0; o[1]  = obj1;
        o[2]  = cx;   o[3]  = cy;  o[4]  = bw;  o[5]  = bh;
        o[6]  = acx;  o[7]  = acy; o[8]  = aww; o[9]  = ahh;
        o[10] = txl;  o[11] = tyl; o[12] = twl; o[13] = thl;
    }
}

extern "C" void kernel_launch(void* const* d_in, const int* in_sizes, int n_in,
                              void* d_out, int out_size, void* d_ws, size_t ws_size,
                              hipStream_t stream) {
    const float* features  = (const float*)d_in[0];
    const float* obj_out   = (const float*)d_in[1];
    const float* reg_out   = (const float*)d_in[2];
    const float* anchors   = (const float*)d_in[3];
    const float* boxes     = (const float*)d_in[4];
    const float* W_fc      = (const float*)d_in[5];
    const float* b_fc      = (const float*)d_in[6];
    const int*   anchor_px = (const int*)d_in[7];
    const int*   field_p   = (const int*)d_in[8];
    float* out = (float*)d_out;

    const int R = in_sizes[3] / 4;   // anchors is (R,4)

    rcnn_head_kernel<<<dim3(R), dim3(256), 0, stream>>>(
        features, obj_out, reg_out, anchors, boxes, W_fc, b_fc,
        anchor_px, field_p, out);
}